// Round 5
// baseline (738.626 us; speedup 1.0000x reference)
//
#include <hip/hip_runtime.h>

#define DD     256   // feature dim
#define CC     100   // num classes
#define NS     8     // column slices of the feature dim
#define SCOLS  32    // columns per slice
#define PADW   33    // padded LDS row stride (floats)
#define RGRPS  256   // row groups (blocks per slice)
#define BT     256   // threads per block

// Workspace layout (bytes):
//   [0, 102400)        : g_sums   (CC*DD f32)
//   [102400, 102800)   : g_counts (CC int)
//   [102800, 102808)   : g_sumsq  (1 double)
//   [102808, 102840)   : probe slots (f32)
//   [102912, +4N)      : cls      (N int)
//   [aligned, ...)     : partials (NS*RGRPS * CC*SCOLS f32)
#define WS_SUMS_OFF   0
#define WS_COUNTS_OFF (CC * DD * 4)
#define WS_SUMSQ_OFF  (WS_COUNTS_OFF + CC * 4)
#define WS_PROBE_OFF  (WS_SUMSQ_OFF + 8)
#define WS_HDR        (WS_PROBE_OFF + 32)
#define WS_CLS_OFF    102912

// ======================= diagnostics =======================================
template<int TAG>
__global__ __launch_bounds__(64) void probe_spin(float* __restrict__ out)
{
    float x = (float)threadIdx.x * 1e-7f + (float)TAG;
    #pragma unroll 16
    for (int i = 0; i < 4096; ++i)          // ~16K-cycle dependent FMA chain
        x = __builtin_fmaf(x, 1.0000001f, 1e-9f);
    if (x == 12345.0f) out[TAG] = x;        // never true; defeats DCE
}

__global__ __launch_bounds__(BT) void probe_stream(
        const float4* __restrict__ src, float* __restrict__ out, int n4)
{
    const int stride = gridDim.x * BT * 4;
    float acc = 0.f;
    for (int i = ((int)blockIdx.x * BT + (int)threadIdx.x) * 4; i < n4; i += stride) {
        float4 a = src[i], b = src[i + 1], c = src[i + 2], d = src[i + 3];
        acc += a.x + a.y + a.z + a.w + b.x + b.y + b.z + b.w
             + c.x + c.y + c.z + c.w + d.x + d.y + d.z + d.w;
    }
    #pragma unroll
    for (int off = 1; off < 64; off <<= 1) acc += __shfl_xor(acc, off);
    if ((threadIdx.x & 63) == 0) unsafeAtomicAdd(out + 2, acc);
}

// ======================= kernel A: per-row argmax ==========================
__global__ __launch_bounds__(BT, 4) void k_argmax(
        const float* __restrict__ labels,
        int*   __restrict__ cls,
        int*   __restrict__ g_counts,
        int N)
{
    __shared__ int s_cnt[CC];
    const int tid = threadIdx.x;
    if (tid < CC) s_cnt[tid] = 0;
    __syncthreads();

    const long long row = (long long)blockIdx.x * BT + tid;
    if (row < (long long)N) {
        const float4* l4 = (const float4*)(labels + row * (long long)CC);
        float4 q[CC / 4];
        #pragma unroll
        for (int j = 0; j < CC / 4; ++j) q[j] = l4[j];   // 25 independent loads
        float best = q[0].x;
        int   bi   = 0;
        #pragma unroll
        for (int j = 0; j < CC / 4; ++j) {               // first-max (strict >)
            if (q[j].x > best) { best = q[j].x; bi = 4 * j; }
            if (q[j].y > best) { best = q[j].y; bi = 4 * j + 1; }
            if (q[j].z > best) { best = q[j].z; bi = 4 * j + 2; }
            if (q[j].w > best) { best = q[j].w; bi = 4 * j + 3; }
        }
        cls[row] = bi;
        atomicAdd(&s_cnt[bi], 1);
    }
    __syncthreads();
    if (tid < CC) {
        const int c = s_cnt[tid];
        if (c) atomicAdd(&g_counts[tid], c);
    }
}

// ======================= kernel B: sliced class-sum accumulate =============
__global__ __launch_bounds__(BT, 4) void k_accum(
        const float* __restrict__ feats,
        const int*   __restrict__ cls,
        float* __restrict__ g_partials,
        float* __restrict__ g_sums,
        double* __restrict__ g_sumsq,
        int use_partials, int N, int rpb)
{
    __shared__ float  s_sums[CC * PADW];   // ~13.2 KB
    __shared__ int    s_cls[256];
    __shared__ double s_red[BT / 64];

    const int tid = threadIdx.x;
    for (int i = tid; i < CC * PADW; i += BT) s_sums[i] = 0.f;

    const int lane  = tid & 63;
    const int wid   = tid >> 6;
    const int slice = blockIdx.x / RGRPS;
    const int rgrp  = blockIdx.x % RGRPS;
    const int d0    = slice * SCOLS;
    const int rsub  = lane >> 3;           // 0..7 : row within 8-row group
    const int cq    = lane & 7;            // 0..7 : float4 within 32-col slice
    const int lr0   = wid * 8 + rsub;      // 0..31: row within 32-row group

    const int base_row = rgrp * rpb;
    float sumsq = 0.f;

    for (int outer = 0; outer < rpb; outer += 256) {
        __syncthreads();                    // protect s_cls reuse (+ s_sums init)
        {
            const int r = base_row + outer + tid;
            s_cls[tid] = (r < N) ? cls[r] : 0;
        }
        __syncthreads();

        // ---- 8 independent batched loads (branchless) ----
        float4 f[8];
        #pragma unroll
        for (int u = 0; u < 8; ++u) {
            const int row = base_row + outer + u * 32 + lr0;
            const int rr  = (row < N) ? row : (N - 1);
            f[u] = *(const float4*)(feats + (size_t)rr * DD + d0 + cq * 4);
            if (row >= N) f[u] = make_float4(0.f, 0.f, 0.f, 0.f);
        }
        int c[8];
        #pragma unroll
        for (int u = 0; u < 8; ++u) c[u] = s_cls[u * 32 + lr0];  // LDS broadcast

        #pragma unroll
        for (int u = 0; u < 8; ++u) {
            sumsq += f[u].x * f[u].x + f[u].y * f[u].y
                   + f[u].z * f[u].z + f[u].w * f[u].w;
            float* dst = &s_sums[c[u] * PADW + cq * 4];
            unsafeAtomicAdd(dst + 0, f[u].x);   // native ds_add_f32
            unsafeAtomicAdd(dst + 1, f[u].y);
            unsafeAtomicAdd(dst + 2, f[u].z);
            unsafeAtomicAdd(dst + 3, f[u].w);
        }
    }

    // ---- sumsq: wave reduce -> block reduce -> one f64 atomic per block ----
    double ds = (double)sumsq;
    #pragma unroll
    for (int off = 1; off < 64; off <<= 1) ds += __shfl_xor(ds, off);
    if (lane == 0) s_red[wid] = ds;
    __syncthreads();   // also drains all ds_add_f32
    if (tid == 0) {
        double t = 0.0;
        #pragma unroll
        for (int i = 0; i < BT / 64; ++i) t += s_red[i];
        atomicAdd(g_sumsq, t);
    }

    // ---- flush this block's [CC][SCOLS] tile ----
    if (use_partials) {
        float* dst = g_partials + (size_t)blockIdx.x * (CC * SCOLS);
        for (int i = tid; i < CC * SCOLS; i += BT)
            dst[i] = s_sums[(i >> 5) * PADW + (i & 31)];
    } else {
        for (int i = tid; i < CC * SCOLS; i += BT) {
            const float s = s_sums[(i >> 5) * PADW + (i & 31)];
            if (s != 0.f)
                unsafeAtomicAdd(&g_sums[(i >> 5) * DD + d0 + (i & 31)], s);
        }
    }
}

// ======================= kernel R: reduce partials =========================
__global__ __launch_bounds__(DD) void k_reduce(
        const float* __restrict__ g_partials,
        float* __restrict__ g_sums)
{
    const int c = blockIdx.x;            // class
    const int d = threadIdx.x;           // global dim 0..255
    const int s = d >> 5;                // slice
    const int col = d & 31;
    const float* p = g_partials + (size_t)(s * RGRPS) * (CC * SCOLS) + c * SCOLS + col;
    double acc = 0.0;
    #pragma unroll 4
    for (int r = 0; r < RGRPS; ++r)
        acc += (double)p[(size_t)r * (CC * SCOLS)];
    g_sums[c * DD + d] = (float)acc;
}

// ======================= finalize ==========================================
__global__ __launch_bounds__(DD) void affinity_finalize(
        const float* __restrict__ g_sums,
        const int*   __restrict__ g_counts,
        const double* __restrict__ g_sumsq,
        float* __restrict__ out)
{
    const int d = threadIdx.x;

    double colsum = 0.0, s2 = 0.0, dot = 0.0, cc = 0.0;
    for (int c = 0; c < CC; ++c) {
        const int    cnt = g_counts[c];
        const float  s   = g_sums[c * DD + d];
        const double center = (cnt > 0 ? (double)s / (double)cnt : 0.0) + 1e-6;
        colsum += center;
        s2     += center * center;
        dot    += center * (double)s;
        cc     += (double)cnt * center * center;
    }
    double interp = s2 - colsum * colsum / (double)CC;

    __shared__ double red0[DD], red1[DD], red2[DD];
    red0[d] = dot; red1[d] = cc; red2[d] = interp;
    __syncthreads();
    for (int off = DD / 2; off > 0; off >>= 1) {
        if (d < off) {
            red0[d] += red0[d + off];
            red1[d] += red1[d + off];
            red2[d] += red2[d + off];
        }
        __syncthreads();
    }
    if (d == 0) {
        const double intra = *g_sumsq - 2.0 * red0[0] + red1[0];
        const double inter = red2[0] / (double)CC;
        out[0] = (float)(intra / (inter + 1e-6));
    }
}

extern "C" void kernel_launch(void* const* d_in, const int* in_sizes, int n_in,
                              void* d_out, int out_size, void* d_ws, size_t ws_size,
                              hipStream_t stream)
{
    const float* feats  = (const float*)d_in[0];
    const float* labels = (const float*)d_in[1];
    const int N = in_sizes[0] / DD;

    float*  g_sums   = (float*)((char*)d_ws + WS_SUMS_OFF);
    int*    g_counts = (int*)((char*)d_ws + WS_COUNTS_OFF);
    double* g_sumsq  = (double*)((char*)d_ws + WS_SUMSQ_OFF);
    float*  g_probe  = (float*)((char*)d_ws + WS_PROBE_OFF);
    int*    cls      = (int*)((char*)d_ws + WS_CLS_OFF);

    const size_t part_off = ((size_t)WS_CLS_OFF + (size_t)N * 4 + 255) & ~(size_t)255;
    float* g_partials = (float*)((char*)d_ws + part_off);

    int rpb = (N + RGRPS - 1) / RGRPS;
    rpb = (rpb + 255) & ~255;              // outer-chunk multiple

    const size_t need = part_off + (size_t)NS * RGRPS * (CC * SCOLS) * 4;
    const int use_partials = (ws_size >= need) ? 1 : 0;

    hipMemsetAsync(d_ws, 0, WS_HDR, stream);

    // ---- diagnostics (also warms clocks + L3 for labels) ----
    probe_spin<0><<<2048,  64, 0, stream>>>(g_probe);
    probe_spin<1><<<16384, 64, 0, stream>>>(g_probe);
    {
        const int n4 = (int)(((long long)N * CC) / 4);
        probe_stream<<<4096, BT, 0, stream>>>((const float4*)labels, g_probe, n4);
    }

    // ---- real work ----
    const int nblocksA = (N + BT - 1) / BT;
    k_argmax<<<nblocksA, BT, 0, stream>>>(labels, cls, g_counts, N);

    k_accum<<<NS * RGRPS, BT, 0, stream>>>(feats, cls, g_partials, g_sums,
                                           g_sumsq, use_partials, N, rpb);
    if (use_partials)
        k_reduce<<<CC, DD, 0, stream>>>(g_partials, g_sums);

    affinity_finalize<<<1, DD, 0, stream>>>(g_sums, g_counts, g_sumsq,
                                            (float*)d_out);
}

// Round 6
// 465.181 us; speedup vs baseline: 1.5878x; 1.5878x over previous
//
#include <hip/hip_runtime.h>

#define DD    256    // feature dim
#define CC    100    // num classes
#define TPB   1024   // threads per block (16 waves)
#define CHUNK 1024   // rows per chunk (== TPB)

// Workspace layout (bytes):
//   [0, 102400)        : g_sums   (CC*DD f32)
//   [102400, 102800)   : g_counts (CC int)
//   [102800, 102808)   : g_sumsq  (1 double)
//   [103424, ...)      : partials (nblocks * CC*DD f32)
#define WS_SUMS_OFF   0
#define WS_COUNTS_OFF (CC * DD * 4)
#define WS_SUMSQ_OFF  (WS_COUNTS_OFF + CC * 4)
#define WS_HDR        (WS_SUMSQ_OFF + 8)
#define WS_PART_OFF   103424

// ---------------- fused pass: argmax + class-sum accumulate -----------------
__global__ __launch_bounds__(TPB) void affinity_pass1(
        const float* __restrict__ feats,
        const float* __restrict__ labels,
        float* __restrict__ g_sums,
        int*   __restrict__ g_counts,
        double* __restrict__ g_sumsq,
        float* __restrict__ g_partials,
        int use_partials, int N, int nblocks)
{
    __shared__ float  s_sums[CC * DD];   // 100 KB -> 1 block/CU
    __shared__ int    s_cls[CHUNK];
    __shared__ int    s_cnt[CC];
    __shared__ double s_red[TPB / 64];

    const int tid = threadIdx.x;
    for (int i = tid; i < CC * DD; i += TPB) s_sums[i] = 0.f;
    if (tid < CC) s_cnt[tid] = 0;
    // first loop-top __syncthreads makes these inits visible

    const int lane  = tid & 63;
    const int wid   = tid >> 6;
    const int wbase = wid * 64;          // this wave's 64 rows within a chunk
    float sumsq = 0.f;

    const int nchunks = (N + CHUNK - 1) / CHUNK;
    for (int ch = blockIdx.x; ch < nchunks; ch += nblocks) {
        const long long base = (long long)ch * CHUNK;
        __syncthreads();   // prev phase-B done with s_cls; inits visible

        // ---------- phase A: one thread per row, register argmax ----------
        {
            const long long row = base + tid;
            int cls = -1;
            if (row < (long long)N) {
                const float4* l4 = (const float4*)(labels + row * (long long)CC);
                float4 q[CC / 4];
                #pragma unroll
                for (int j = 0; j < CC / 4; ++j) q[j] = l4[j];  // 25 indep loads
                float best = q[0].x;
                int   bi   = 0;
                #pragma unroll
                for (int j = 0; j < CC / 4; ++j) {              // first-max (strict >)
                    if (q[j].x > best) { best = q[j].x; bi = 4 * j; }
                    if (q[j].y > best) { best = q[j].y; bi = 4 * j + 1; }
                    if (q[j].z > best) { best = q[j].z; bi = 4 * j + 2; }
                    if (q[j].w > best) { best = q[j].w; bi = 4 * j + 3; }
                }
                cls = bi;
                atomicAdd(&s_cnt[bi], 1);                       // native int LDS atomic
            }
            s_cls[tid] = cls;
        }
        __syncthreads();

        // ---------- phase B: wave per 4 rows, native ds_add_f32 ------------
        for (int g = 0; g < 16; ++g) {
            const int r0 = wbase + g * 4;
            const int4 c4 = *(const int4*)&s_cls[r0];           // broadcast read
            const int cls_[4] = { c4.x, c4.y, c4.z, c4.w };

            float f[4][4];
            #pragma unroll
            for (int r = 0; r < 4; ++r) {
                const long long row = base + r0 + r;
                const float* frow = feats + ((row < (long long)N) ? row : 0) * (long long)DD;
                #pragma unroll
                for (int j = 0; j < 4; ++j)
                    f[r][j] = frow[lane + 64 * j];              // coalesced 256B/instr
            }

            #pragma unroll
            for (int r = 0; r < 4; ++r) {
                if (cls_[r] < 0) continue;                      // OOB row
                sumsq += f[r][0] * f[r][0] + f[r][1] * f[r][1]
                       + f[r][2] * f[r][2] + f[r][3] * f[r][3];
                float* dst = &s_sums[cls_[r] * DD + lane];      // bank = lane%32, 2-way only
                unsafeAtomicAdd(dst +   0, f[r][0]);            // ds_add_f32, no return
                unsafeAtomicAdd(dst +  64, f[r][1]);
                unsafeAtomicAdd(dst + 128, f[r][2]);
                unsafeAtomicAdd(dst + 192, f[r][3]);
            }
        }
    }

    // ---- sumsq: wave reduce -> block reduce -> one f64 atomic per block ----
    double ds = (double)sumsq;
    #pragma unroll
    for (int off = 1; off < 64; off <<= 1) ds += __shfl_xor(ds, off);
    if (lane == 0) s_red[wid] = ds;
    __syncthreads();   // also drains all ds_add_f32
    if (tid == 0) {
        double t = 0.0;
        #pragma unroll
        for (int i = 0; i < TPB / 64; ++i) t += s_red[i];
        atomicAdd(g_sumsq, t);
    }

    // ---- flush ----
    if (use_partials) {
        float* dst = g_partials + (size_t)blockIdx.x * (CC * DD);
        for (int i = tid; i < CC * DD; i += TPB) dst[i] = s_sums[i];
    } else {
        for (int i = tid; i < CC * DD; i += TPB) {
            const float s = s_sums[i];
            if (s != 0.f) unsafeAtomicAdd(&g_sums[i], s);
        }
    }
    if (tid < CC) {
        const int c = s_cnt[tid];
        if (c) atomicAdd(&g_counts[tid], c);
    }
}

// ---------------- reduce partials -> g_sums ---------------------------------
__global__ __launch_bounds__(DD) void k_reduce(
        const float* __restrict__ g_partials,
        float* __restrict__ g_sums,
        int nblocks)
{
    const int c = blockIdx.x;            // class
    const int d = threadIdx.x;           // dim
    const float* p = g_partials + c * DD + d;
    double acc = 0.0;
    for (int b = 0; b < nblocks; ++b)
        acc += (double)p[(size_t)b * (CC * DD)];   // coalesced across threads
    g_sums[c * DD + d] = (float)acc;
}

// ---------------- finalize ---------------------------------------------------
__global__ __launch_bounds__(DD) void affinity_finalize(
        const float* __restrict__ g_sums,
        const int*   __restrict__ g_counts,
        const double* __restrict__ g_sumsq,
        float* __restrict__ out)
{
    const int d = threadIdx.x;

    double colsum = 0.0, s2 = 0.0, dot = 0.0, cc = 0.0;
    for (int c = 0; c < CC; ++c) {
        const int    cnt = g_counts[c];
        const float  s   = g_sums[c * DD + d];
        const double center = (cnt > 0 ? (double)s / (double)cnt : 0.0) + 1e-6;
        colsum += center;
        s2     += center * center;
        dot    += center * (double)s;
        cc     += (double)cnt * center * center;
    }
    double interp = s2 - colsum * colsum / (double)CC;

    __shared__ double red0[DD], red1[DD], red2[DD];
    red0[d] = dot; red1[d] = cc; red2[d] = interp;
    __syncthreads();
    for (int off = DD / 2; off > 0; off >>= 1) {
        if (d < off) {
            red0[d] += red0[d + off];
            red1[d] += red1[d + off];
            red2[d] += red2[d + off];
        }
        __syncthreads();
    }
    if (d == 0) {
        const double intra = *g_sumsq - 2.0 * red0[0] + red1[0];
        const double inter = red2[0] / (double)CC;
        out[0] = (float)(intra / (inter + 1e-6));
    }
}

extern "C" void kernel_launch(void* const* d_in, const int* in_sizes, int n_in,
                              void* d_out, int out_size, void* d_ws, size_t ws_size,
                              hipStream_t stream)
{
    const float* feats  = (const float*)d_in[0];
    const float* labels = (const float*)d_in[1];
    const int N = in_sizes[0] / DD;

    float*  g_sums     = (float*)((char*)d_ws + WS_SUMS_OFF);
    int*    g_counts   = (int*)((char*)d_ws + WS_COUNTS_OFF);
    double* g_sumsq    = (double*)((char*)d_ws + WS_SUMSQ_OFF);
    float*  g_partials = (float*)((char*)d_ws + WS_PART_OFF);

    // Adapt the grid to the ACTUAL device (partitioned MI355X gives fewer CUs).
    // Host-side attribute query: no stream interaction -> graph-capture safe.
    int dev = 0, ncu = 0;
    hipGetDevice(&dev);
    if (hipDeviceGetAttribute(&ncu, hipDeviceAttributeMultiprocessorCount, dev)
            != hipSuccess || ncu <= 0)
        ncu = 64;
    const int nchunks = (N + CHUNK - 1) / CHUNK;
    int NB = (ncu < nchunks) ? ncu : nchunks;    // one resident block per CU
    if (NB < 1) NB = 1;

    const size_t need = (size_t)WS_PART_OFF + (size_t)NB * (CC * DD) * 4;
    const int use_partials = (ws_size >= need) ? 1 : 0;

    hipMemsetAsync(d_ws, 0, WS_HDR, stream);     // zero sums/counts/sumsq

    affinity_pass1<<<NB, TPB, 0, stream>>>(feats, labels, g_sums, g_counts,
                                           g_sumsq, g_partials, use_partials,
                                           N, NB);
    if (use_partials)
        k_reduce<<<CC, DD, 0, stream>>>(g_partials, g_sums, NB);

    affinity_finalize<<<1, DD, 0, stream>>>(g_sums, g_counts, g_sumsq,
                                            (float*)d_out);
}